// Round 4
// baseline (339.993 us; speedup 1.0000x reference)
//
#include <hip/hip_runtime.h>

#define N_IMG 4
#define E_DIM 16
#define P_PIX 320000
#define G_PIX (P_PIX / 4)     // 80000 float4 groups per image-channel
#define C_CLS 20
#define CK 19                 // classes 1..19 (IGNORE = 0 excluded)
#define NREP 8                // replicated LDS accumulators
#define REPS 9                // replica stride: 9 invertible mod 32 -> classes on distinct banks
#define MSTRIDE 17            // mean-tile stride: 17 invertible mod 32

// ws layout (floats): sums[n][c][e], counts[n][c], means[n][c][e], loss
#define SUMS_OFF 0
#define CNT_OFF  (N_IMG * C_CLS * E_DIM)            // 1280
#define MEAN_OFF (CNT_OFF + N_IMG * C_CLS)          // 1360
#define LOSS_OFF (MEAN_OFF + N_IMG * C_CLS * E_DIM) // 2640
#define WS_FLOATS (LOSS_OFF + 1)

#define SL 40                 // k_sums slices per (e,n)
#define K1_STRIDE (SL * 256)

// ---------------- Kernel 1: per-class sums + counts ----------------
// channel-major; LDS atomicAdd scatter (8 replicas); 2-stage load pipeline
__global__ void k_sums(const float* __restrict__ emb, const int* __restrict__ target,
                       float* __restrict__ ws) {
    __shared__ float lsum[C_CLS * REPS];
    __shared__ float lcnt[C_CLS * REPS];
    const int slice = blockIdx.x;   // 0..SL-1
    const int e     = blockIdx.y;   // 0..15
    const int n     = blockIdx.z;   // 0..3
    const int tid   = threadIdx.x;
    const int rep   = tid & (NREP - 1);

    for (int i = tid; i < C_CLS * REPS; i += 256) { lsum[i] = 0.f; lcnt[i] = 0.f; }
    __syncthreads();

    const float4* emb4 = (const float4*)emb + (size_t)(n * E_DIM + e) * G_PIX;
    const int4*   tgt4 = (const int4*)target + (size_t)n * G_PIX;
    const bool do_cnt = (e == 0);

    int g = slice * 256 + tid;
    bool valid = g < G_PIX;
    int4 lb = make_int4(0, 0, 0, 0);
    float4 v = make_float4(0.f, 0.f, 0.f, 0.f);
    if (valid) { lb = tgt4[g]; v = emb4[g]; }

    while (valid) {
        // prefetch next iteration before consuming current (keeps 2 loads in flight)
        const int gn = g + K1_STRIDE;
        const bool vn = gn < G_PIX;
        int4 lbn = lb; float4 vnx = v;
        if (vn) { lbn = tgt4[gn]; vnx = emb4[gn]; }

        atomicAdd(&lsum[lb.x * REPS + rep], v.x);
        atomicAdd(&lsum[lb.y * REPS + rep], v.y);
        atomicAdd(&lsum[lb.z * REPS + rep], v.z);
        atomicAdd(&lsum[lb.w * REPS + rep], v.w);
        if (do_cnt) {
            atomicAdd(&lcnt[lb.x * REPS + rep], 1.f);
            atomicAdd(&lcnt[lb.y * REPS + rep], 1.f);
            atomicAdd(&lcnt[lb.z * REPS + rep], 1.f);
            atomicAdd(&lcnt[lb.w * REPS + rep], 1.f);
        }
        lb = lbn; v = vnx; g = gn; valid = vn;
    }
    __syncthreads();

    if (tid < C_CLS) {
        float s = 0.f;
#pragma unroll
        for (int r = 0; r < NREP; r++) s += lsum[tid * REPS + r];
        atomicAdd(ws + SUMS_OFF + (n * C_CLS + tid) * E_DIM + e, s);
        if (do_cnt) {
            float cs = 0.f;
#pragma unroll
            for (int r = 0; r < NREP; r++) cs += lcnt[tid * REPS + r];
            atomicAdd(ws + CNT_OFF + n * C_CLS + tid, cs);
        }
    }
}

// -------- Kernel 2: means + distance(push) term + regularizer --------
__global__ void k_means_dist(float* __restrict__ ws) {
    __shared__ float lmean[C_CLS * E_DIM];
    __shared__ float red[256];
    const int n = blockIdx.x, tid = threadIdx.x;

    const float* gsum = ws + SUMS_OFF + n * C_CLS * E_DIM;
    const float* gcnt = ws + CNT_OFF + n * C_CLS;
    float* gmean = ws + MEAN_OFF + n * C_CLS * E_DIM;

    for (int i = tid; i < C_CLS * E_DIM; i += blockDim.x) {
        const int c = i / E_DIM;
        const float cnt = gcnt[c];
        const float m = (cnt > 0.f) ? gsum[i] / cnt : 0.f;
        lmean[i] = m;
        gmean[i] = m;
    }
    __syncthreads();

    float acc = 0.f;
    for (int idx = tid; idx < CK * CK; idx += blockDim.x) {
        const int i = idx / CK + 1, j = idx % CK + 1;
        if (i != j) {
            float sq = 0.f;
#pragma unroll
            for (int e = 0; e < E_DIM; e++) {
                const float d = lmean[i * E_DIM + e] - lmean[j * E_DIM + e];
                sq += d * d;
            }
            const float dm = sqrtf(sq);
            const float h = fmaxf(3.0f - dm, 0.f);   // 2*DELTA_DIST = 3
            acc += h * h;
        }
    }
    acc *= 1.0f / (float)(CK * (CK - 1));            // BETA = 1

    float racc = 0.f;
    for (int c = tid + 1; c < C_CLS; c += blockDim.x) {
        float sq = 0.f;
#pragma unroll
        for (int e = 0; e < E_DIM; e++) {
            const float m = lmean[c * E_DIM + e];
            sq += m * m;
        }
        racc += sqrtf(sq);
    }
    acc += 0.001f * racc / (float)CK;                // GAMMA = 0.001

    red[tid] = acc;
    __syncthreads();
    for (int s = blockDim.x / 2; s > 0; s >>= 1) {
        if (tid < s) red[tid] += red[tid + s];
        __syncthreads();
    }
    if (tid == 0) atomicAdd(ws + LOSS_OFF, red[0]);
}

// ---------------- Kernel 3: variance (pull) term ----------------
// block = 256 pixels of one image; cooperative per-channel coalesced staging into LDS,
// then one pixel per thread from LDS (stride-1, conflict-free).
__global__ void k_var(const float* __restrict__ emb, const int* __restrict__ target,
                      float* __restrict__ ws) {
    __shared__ float tile[E_DIM * 256];        // [e][pix], 16 KB
    __shared__ float lmean[C_CLS * MSTRIDE];
    __shared__ float lw[C_CLS];
    __shared__ float red[256];
    const int b = blockIdx.x;                  // 0..1249
    const int n = blockIdx.y;
    const int tid = threadIdx.x;
    const int wave = tid >> 6, lane = tid & 63;

    // means + per-class weights -> LDS
    const float* gmean = ws + MEAN_OFF + n * C_CLS * E_DIM;
    const float* gcnt  = ws + CNT_OFF + n * C_CLS;
    for (int i = tid; i < C_CLS * E_DIM; i += 256) {
        const int c = i >> 4, e = i & 15;
        lmean[c * MSTRIDE + e] = gmean[i];
    }
    if (tid < C_CLS) {
        const float cnt = gcnt[tid];
        lw[tid] = (tid != 0 && cnt > 0.f) ? 1.0f / (cnt * (float)CK) : 0.f;
    }

    // stage 256 pixels x 16 channels: wave w loads channels 4w..4w+3 (64 float4 each)
    const float4* emb4 = (const float4*)emb + (size_t)n * E_DIM * G_PIX;
    const int gbase = b * 64;
#pragma unroll
    for (int j = 0; j < 4; j++) {
        const int c = wave * 4 + j;
        const float4 vv = emb4[(size_t)c * G_PIX + gbase + lane];
        ((float4*)tile)[c * 64 + lane] = vv;   // tile[c][4*lane .. 4*lane+3]
    }
    const int lab = target[(size_t)n * P_PIX + b * 256 + tid];
    __syncthreads();

    float sq = 0.f;
    const int mb = lab * MSTRIDE;
#pragma unroll
    for (int e = 0; e < E_DIM; e++) {
        const float d = tile[e * 256 + tid] - lmean[mb + e];
        sq += d * d;
    }
    const float h = fmaxf(sqrtf(sq) - 0.5f, 0.f);  // DELTA_VAR = 0.5
    float acc = h * h * lw[lab];                   // lw[0]=0 masks IGNORE

    red[tid] = acc;
    __syncthreads();
    for (int s = 128; s > 0; s >>= 1) {
        if (tid < s) red[tid] += red[tid + s];
        __syncthreads();
    }
    if (tid == 0) atomicAdd(ws + LOSS_OFF, red[0]);
}

// ---------------- Kernel 4: finalize ----------------
__global__ void k_fin(const float* __restrict__ ws, float* __restrict__ out) {
    out[0] = ws[LOSS_OFF] * 0.25f;  // mean over 4 images
}

extern "C" void kernel_launch(void* const* d_in, const int* in_sizes, int n_in,
                              void* d_out, int out_size, void* d_ws, size_t ws_size,
                              hipStream_t stream) {
    const float* emb = (const float*)d_in[0];
    const int* target = (const int*)d_in[1];
    float* out = (float*)d_out;
    float* ws = (float*)d_ws;

    hipMemsetAsync(d_ws, 0, WS_FLOATS * sizeof(float), stream);

    dim3 gs(SL, E_DIM, N_IMG);                     // 2560 blocks
    k_sums<<<gs, 256, 0, stream>>>(emb, target, ws);
    k_means_dist<<<N_IMG, 256, 0, stream>>>(ws);
    dim3 gv(G_PIX / 64, N_IMG);                    // 1250 x 4 blocks
    k_var<<<gv, 256, 0, stream>>>(emb, target, ws);
    k_fin<<<1, 1, 0, stream>>>(ws, out);
}

// Round 5
// 245.145 us; speedup vs baseline: 1.3869x; 1.3869x over previous
//
#include <hip/hip_runtime.h>

#define N_IMG 4
#define E_DIM 16
#define P_PIX 320000
#define G_PIX (P_PIX / 4)     // 80000 float4 groups per image
#define C_CLS 20
#define CK 19                 // classes 1..19 (IGNORE = 0 excluded)
#define MSTRIDE 17            // mean-tile stride: 17 invertible mod 32
#define CSTR 3                // class stride in accumulator LDS: 3 invertible mod 32

// ws layout (floats): sums[n][c][e], counts[n][c], means[n][c][e], loss
#define SUMS_OFF 0
#define CNT_OFF  (N_IMG * C_CLS * E_DIM)            // 1280
#define MEAN_OFF (CNT_OFF + N_IMG * C_CLS)          // 1360
#define LOSS_OFF (MEAN_OFF + N_IMG * C_CLS * E_DIM) // 2640
#define WS_FLOATS (LOSS_OFF + 1)

// ---------------- Kernel 1: per-class sums + counts (pixel-major) ----------------
// One float4-group per thread. All 17 loads issued unconditionally before any
// consumer (forces MLP; rounds 2/4 showed guarded/atomic-fed loads collapse to
// VGPR=16 and serialize). Scatter via LDS atomics: addr = e*64 + c*3 + (tid&1)
// -> 20 classes hit 20 distinct banks (3 inv mod 32), 2 replicas.
__global__ __launch_bounds__(256, 2) void k_sums(const float* __restrict__ emb,
                                                 const int* __restrict__ target,
                                                 float* __restrict__ ws) {
    __shared__ float lsum[E_DIM * 64];   // [e][c*3+rep], 4 KB
    __shared__ float lcnt[64];
    const int n = blockIdx.y;
    const int tid = threadIdx.x;
    const int rep = tid & 1;

    for (int i = tid; i < E_DIM * 64; i += 256) lsum[i] = 0.f;
    if (tid < 64) lcnt[tid] = 0.f;
    __syncthreads();

    const int g = blockIdx.x * 256 + tid;
    if (g < G_PIX) {
        const int4 lb = ((const int4*)target)[(size_t)n * G_PIX + g];
        const float4* emb4 = (const float4*)emb + (size_t)n * E_DIM * G_PIX;
        float4 v[E_DIM];
#pragma unroll
        for (int e = 0; e < E_DIM; e++) v[e] = emb4[(size_t)e * G_PIX + g];

        const int ax = lb.x * CSTR + rep, ay = lb.y * CSTR + rep;
        const int az = lb.z * CSTR + rep, aw = lb.w * CSTR + rep;
        atomicAdd(&lcnt[ax], 1.f);
        atomicAdd(&lcnt[ay], 1.f);
        atomicAdd(&lcnt[az], 1.f);
        atomicAdd(&lcnt[aw], 1.f);
#pragma unroll
        for (int e = 0; e < E_DIM; e++) {
            atomicAdd(&lsum[e * 64 + ax], v[e].x);
            atomicAdd(&lsum[e * 64 + ay], v[e].y);
            atomicAdd(&lsum[e * 64 + az], v[e].z);
            atomicAdd(&lsum[e * 64 + aw], v[e].w);
        }
    }
    __syncthreads();

    for (int i = tid; i < C_CLS * E_DIM; i += 256) {
        const int c = i >> 4, e = i & 15;
        const float s = lsum[e * 64 + c * CSTR] + lsum[e * 64 + c * CSTR + 1];
        atomicAdd(ws + SUMS_OFF + (size_t)(n * C_CLS + c) * E_DIM + e, s);
    }
    if (tid < C_CLS) {
        atomicAdd(ws + CNT_OFF + n * C_CLS + tid, lcnt[tid * CSTR] + lcnt[tid * CSTR + 1]);
    }
}

// -------- Kernel 2: means + distance(push) term + regularizer --------
__global__ void k_means_dist(float* __restrict__ ws) {
    __shared__ float lmean[C_CLS * E_DIM];
    __shared__ float red[256];
    const int n = blockIdx.x, tid = threadIdx.x;

    const float* gsum = ws + SUMS_OFF + n * C_CLS * E_DIM;
    const float* gcnt = ws + CNT_OFF + n * C_CLS;
    float* gmean = ws + MEAN_OFF + n * C_CLS * E_DIM;

    for (int i = tid; i < C_CLS * E_DIM; i += blockDim.x) {
        const int c = i / E_DIM;
        const float cnt = gcnt[c];
        const float m = (cnt > 0.f) ? gsum[i] / cnt : 0.f;
        lmean[i] = m;
        gmean[i] = m;
    }
    __syncthreads();

    float acc = 0.f;
    for (int idx = tid; idx < CK * CK; idx += blockDim.x) {
        const int i = idx / CK + 1, j = idx % CK + 1;
        if (i != j) {
            float sq = 0.f;
#pragma unroll
            for (int e = 0; e < E_DIM; e++) {
                const float d = lmean[i * E_DIM + e] - lmean[j * E_DIM + e];
                sq += d * d;
            }
            const float dm = sqrtf(sq);
            const float h = fmaxf(3.0f - dm, 0.f);   // 2*DELTA_DIST = 3
            acc += h * h;
        }
    }
    acc *= 1.0f / (float)(CK * (CK - 1));            // BETA = 1

    float racc = 0.f;
    for (int c = tid + 1; c < C_CLS; c += blockDim.x) {
        float sq = 0.f;
#pragma unroll
        for (int e = 0; e < E_DIM; e++) {
            const float m = lmean[c * E_DIM + e];
            sq += m * m;
        }
        racc += sqrtf(sq);
    }
    acc += 0.001f * racc / (float)CK;                // GAMMA = 0.001

    red[tid] = acc;
    __syncthreads();
    for (int s = blockDim.x / 2; s > 0; s >>= 1) {
        if (tid < s) red[tid] += red[tid + s];
        __syncthreads();
    }
    if (tid == 0) atomicAdd(ws + LOSS_OFF, red[0]);
}

// ---------------- Kernel 3: variance (pull) term ----------------
// Same forced-MLP load structure as k_sums; shuffle-based block reduction.
__global__ __launch_bounds__(256, 2) void k_var(const float* __restrict__ emb,
                                                const int* __restrict__ target,
                                                float* __restrict__ ws) {
    __shared__ float lmean[C_CLS * MSTRIDE];
    __shared__ float lw[C_CLS];
    __shared__ float wred[4];
    const int n = blockIdx.y, tid = threadIdx.x;

    const float* gmean = ws + MEAN_OFF + n * C_CLS * E_DIM;
    const float* gcnt  = ws + CNT_OFF + n * C_CLS;
    for (int i = tid; i < C_CLS * E_DIM; i += 256) {
        const int c = i >> 4, e = i & 15;
        lmean[c * MSTRIDE + e] = gmean[i];
    }
    if (tid < C_CLS) {
        const float cnt = gcnt[tid];
        lw[tid] = (tid != 0 && cnt > 0.f) ? 1.0f / (cnt * (float)CK) : 0.f;
    }
    __syncthreads();

    float acc = 0.f;
    const int g = blockIdx.x * 256 + tid;
    if (g < G_PIX) {
        const int4 lb = ((const int4*)target)[(size_t)n * G_PIX + g];
        const float4* emb4 = (const float4*)emb + (size_t)n * E_DIM * G_PIX;
        float4 v[E_DIM];
#pragma unroll
        for (int e = 0; e < E_DIM; e++) v[e] = emb4[(size_t)e * G_PIX + g];

        const int bx = lb.x * MSTRIDE, by = lb.y * MSTRIDE;
        const int bz = lb.z * MSTRIDE, bw = lb.w * MSTRIDE;
        float sx = 0.f, sy = 0.f, sz = 0.f, sw = 0.f;
#pragma unroll
        for (int e = 0; e < E_DIM; e++) {
            float d;
            d = v[e].x - lmean[bx + e]; sx += d * d;
            d = v[e].y - lmean[by + e]; sy += d * d;
            d = v[e].z - lmean[bz + e]; sz += d * d;
            d = v[e].w - lmean[bw + e]; sw += d * d;
        }
        float h;
        h = fmaxf(sqrtf(sx) - 0.5f, 0.f); acc += h * h * lw[lb.x];  // DELTA_VAR = 0.5
        h = fmaxf(sqrtf(sy) - 0.5f, 0.f); acc += h * h * lw[lb.y];
        h = fmaxf(sqrtf(sz) - 0.5f, 0.f); acc += h * h * lw[lb.z];
        h = fmaxf(sqrtf(sw) - 0.5f, 0.f); acc += h * h * lw[lb.w];  // lw[0]=0 masks IGNORE
    }

    // wave shuffle reduction, then cross-wave via 4 LDS slots
#pragma unroll
    for (int off = 32; off > 0; off >>= 1) acc += __shfl_down(acc, off, 64);
    if ((tid & 63) == 0) wred[tid >> 6] = acc;
    __syncthreads();
    if (tid == 0) atomicAdd(ws + LOSS_OFF, wred[0] + wred[1] + wred[2] + wred[3]);
}

// ---------------- Kernel 4: finalize ----------------
__global__ void k_fin(const float* __restrict__ ws, float* __restrict__ out) {
    out[0] = ws[LOSS_OFF] * 0.25f;  // mean over 4 images
}

extern "C" void kernel_launch(void* const* d_in, const int* in_sizes, int n_in,
                              void* d_out, int out_size, void* d_ws, size_t ws_size,
                              hipStream_t stream) {
    const float* emb = (const float*)d_in[0];
    const int* target = (const int*)d_in[1];
    float* out = (float*)d_out;
    float* ws = (float*)d_ws;

    hipMemsetAsync(d_ws, 0, WS_FLOATS * sizeof(float), stream);

    dim3 gp((G_PIX + 255) / 256, N_IMG);   // 313 x 4 blocks
    k_sums<<<gp, 256, 0, stream>>>(emb, target, ws);
    k_means_dist<<<N_IMG, 256, 0, stream>>>(ws);
    k_var<<<gp, 256, 0, stream>>>(emb, target, ws);
    k_fin<<<1, 1, 0, stream>>>(ws, out);
}